// Round 11
// baseline (180.769 us; speedup 1.0000x reference)
//
#include <hip/hip_runtime.h>
#include <hip/hip_bf16.h>

constexpr int PAD_T = 10, BOS_T = 11, EOS_T = 12, ROW_T = 13, SEP_T = 14;
constexpr int Bc = 16, Tc = 4096, Dc = 512;
constexpr int MAXH = 30, MAXW = 30;

typedef float fvec4 __attribute__((ext_vector_type(4)));

// Scratch in module-scope device globals (the d_ws poison is unconditional,
// so d_ws is unused entirely). scan_pre_kernel fully rewrites all three
// every launch before fuse_ln_kernel reads them: no stale-data hazard.
__device__ __align__(16) int   g_packed[Bc * Tc];        // 256 KiB
__device__ __align__(16) float g_frow[MAXH * Dc];        // 60 KiB
__device__ __align__(16) float g_fcol[MAXW * Dc];        // 60 KiB

// Composable transition summary of a token chunk.
struct Summ { int r, c0, c1, g0, g1, rk, ck; };

__device__ inline void tok_update(int tok, Summ& s) {
    if (tok == BOS_T)      { s.g0 = 1; s.g1 = 1; s.r = 0; s.c0 = 0; s.c1 = 0; s.rk = 0; s.ck = 0; }
    else if (tok == SEP_T) { s.r = 0; s.c0 = 0; s.c1 = 0; s.rk = 0; s.ck = 0; }
    else if (tok == ROW_T) { s.r += 1; s.c0 = 0; s.c1 = 0; s.ck = 0; }
    else if (tok == EOS_T || tok == PAD_T) { s.g0 = 0; s.g1 = 0; }
    else { s.c0 += s.g0; s.c1 += s.g1; }   // digit 0..9
}

__device__ inline Summ compose(const Summ& a, const Summ& b) {
    Summ o;
    o.g0 = a.g0 ? b.g1 : b.g0;
    o.g1 = a.g1 ? b.g1 : b.g0;
    o.r  = b.rk ? a.r + b.r : b.r;
    o.rk = a.rk & b.rk;
    int cm0 = a.g0 ? b.c1 : b.c0;
    int cm1 = a.g1 ? b.c1 : b.c0;
    o.c0 = b.ck ? a.c0 + cm0 : cm0;
    o.c1 = b.ck ? a.c1 + cm1 : cm1;
    o.ck = a.ck & b.ck;
    return o;
}

__device__ inline void apply_state(const Summ& s, int& r, int& c, int& g) {
    int cm = g ? s.c1 : s.c0;
    r = s.rk ? r + s.r : s.r;
    c = s.ck ? c + cm : cm;
    g = g ? s.g1 : s.g0;
}

// ---------------------------------------------------------------------------
// Dispatch 1 (merged): blocks 0..15 = parallel automaton scan; blocks 16..75 =
// einsum collapse Frow = row_table @ W[:, :256]^T, Fcol = col_table @ W[:, 256:]^T.
// ---------------------------------------------------------------------------
__global__ __launch_bounds__(1024) void scan_pre_kernel(
        const int* __restrict__ ids,
        const float* __restrict__ row_table, const float* __restrict__ col_table,
        const float* __restrict__ w) {
    if (blockIdx.x < 16) {
        const int b = blockIdx.x;
        const int tid = threadIdx.x;          // 0..1023
        const int lane = tid & 63, wid = tid >> 6;

        const int4 tk4 = *(const int4*)(ids + b * Tc + tid * 4);
        int tks[4] = {tk4.x, tk4.y, tk4.z, tk4.w};

        Summ s{0, 0, 0, 0, 1, 1, 1};
#pragma unroll
        for (int j = 0; j < 4; ++j) tok_update(tks[j], s);

        Summ inc = s;
#pragma unroll
        for (int d = 1; d < 64; d <<= 1) {
            Summ o;
            o.r  = __shfl_up(inc.r, d);
            o.c0 = __shfl_up(inc.c0, d);
            o.c1 = __shfl_up(inc.c1, d);
            o.g0 = __shfl_up(inc.g0, d);
            o.g1 = __shfl_up(inc.g1, d);
            o.rk = __shfl_up(inc.rk, d);
            o.ck = __shfl_up(inc.ck, d);
            if (lane >= d) inc = compose(o, inc);
        }

        __shared__ int lsum[16][7];
        if (lane == 63) {
            lsum[wid][0] = inc.r;  lsum[wid][1] = inc.c0; lsum[wid][2] = inc.c1;
            lsum[wid][3] = inc.g0; lsum[wid][4] = inc.g1;
            lsum[wid][5] = inc.rk; lsum[wid][6] = inc.ck;
        }
        __syncthreads();

        int wr = 0, wc = 0, wg = 0;
        for (int w2 = 0; w2 < wid; ++w2) {
            Summ t;
            t.r  = lsum[w2][0]; t.c0 = lsum[w2][1]; t.c1 = lsum[w2][2];
            t.g0 = lsum[w2][3]; t.g1 = lsum[w2][4];
            t.rk = lsum[w2][5]; t.ck = lsum[w2][6];
            apply_state(t, wr, wc, wg);
        }

        Summ ex;
        ex.r  = __shfl_up(inc.r, 1);  ex.c0 = __shfl_up(inc.c0, 1);
        ex.c1 = __shfl_up(inc.c1, 1); ex.g0 = __shfl_up(inc.g0, 1);
        ex.g1 = __shfl_up(inc.g1, 1); ex.rk = __shfl_up(inc.rk, 1);
        ex.ck = __shfl_up(inc.ck, 1);
        if (lane == 0) { ex = Summ{0, 0, 0, 0, 1, 1, 1}; }
        int row = wr, col = wc, grid = wg;
        apply_state(ex, row, col, grid);

        int o4[4];
#pragma unroll
        for (int j = 0; j < 4; ++j) {
            int tok = tks[j];
            int gc = grid & (tok <= 9);
            int er = gc ? min(row, MAXH - 1) : 0;
            int ec = gc ? min(col, MAXW - 1) : 0;
            o4[j] = (er << 5) | ec;
            if (tok == BOS_T)      { grid = 1; row = 0; col = 0; }
            else if (tok == SEP_T) { row = 0; col = 0; }
            else if (tok == ROW_T) { row += 1; col = 0; }
            else if (tok == EOS_T || tok == PAD_T) { grid = 0; }
            else { col += gc; }
        }
        *(int4*)(g_packed + b * Tc + tid * 4) = make_int4(o4[0], o4[1], o4[2], o4[3]);
    } else {
        const int blk = blockIdx.x - 16;
        const int which = blk / 30;            // 0 -> Frow, 1 -> Fcol
        const int rr = blk % 30;
        const float* src = which ? (col_table + rr * 256) : (row_table + rr * 256);
        float* dst = which ? (g_fcol + rr * Dc) : (g_frow + rr * Dc);
        const int doff = which ? 256 : 0;

        __shared__ __align__(16) float sv[256];
        __shared__ float part[512];
        if (threadIdx.x < 256) sv[threadIdx.x] = src[threadIdx.x];
        __syncthreads();

        const int e    = threadIdx.x & 511;
        const int half = threadIdx.x >> 9;     // split-k: 2 threads per output
        const float4* a4 = (const float4*)sv + half * 32;
        const float4* w4 = (const float4*)(w + (size_t)e * Dc + doff) + half * 32;
        float acc = 0.f;
#pragma unroll 8
        for (int k = 0; k < 32; ++k) {
            float4 a = a4[k];
            float4 wb = w4[k];
            acc += a.x * wb.x + a.y * wb.y + a.z * wb.z + a.w * wb.w;
        }
        if (half) part[e] = acc;
        __syncthreads();
        if (!half) dst[e] = acc + part[e];
    }
}

// ---------------------------------------------------------------------------
// Dispatch 2: fused embed-add + LayerNorm. Round-10 structure (one
// contiguous 8KB store run per wave, linear block tiling, dense dLo/dHi
// lane mapping) with NONTEMPORAL stores. Rationale: stores are now fully
// dense (each wave instruction = 16 complete 64B sectors, contiguous) and
// linearly tiled, so NT streaming cannot amplify (round 2's 2.3x was
// partial-sector interleave); bypassing L2 removes 134MB of dirty-line
// evictions that compete with the read-miss stream (ws poison flushes
// L2+L3 every iteration, so all table reads miss). This is the last
// difference vs the 6.5TB/s fill's store path.
// ---------------------------------------------------------------------------
__global__ __launch_bounds__(256) void fuse_ln_kernel(
        const int* __restrict__ ids,
        const float* __restrict__ token_table, const float* __restrict__ pos_table,
        const float* __restrict__ gamma, const float* __restrict__ beta,
        float* __restrict__ out) {
    const int wave = threadIdx.x >> 6;
    const int lane = threadIdx.x & 63;
    const int g2 = blockIdx.x * 4 + wave;    // wave id in [0, 16384)
    const int b  = g2 >> 10;                 // batch row, SLOWEST (store locality)
    const int t  = (g2 & 1023) << 2;         // t..t+3, FASTEST across waves
    const int idx = b * Tc + t;              // first of 4 consecutive rows
    const int dLo = lane * 4;                // dense low half  [0,256)
    const int dHi = 256 + lane * 4;          // dense high half [256,512)

    // 4 token ids + 4 packed coords in two int4 loads
    const int4 tk4 = *(const int4*)(ids + idx);
    const int4 pk4 = *(const int4*)(g_packed + idx);
    const int tk[4] = {tk4.x, tk4.y, tk4.z, tk4.w};
    const int pk[4] = {pk4.x, pk4.y, pk4.z, pk4.w};

    // pos rows t..t+3 (dense 1KB per instruction)
    const float* pt = pos_table + (size_t)t * Dc;
    fvec4 pLo[4], pHi[4];
#pragma unroll
    for (int k = 0; k < 4; ++k) {
        pLo[k] = *(const fvec4*)(pt + k * Dc + dLo);
        pHi[k] = *(const fvec4*)(pt + k * Dc + dHi);
    }

    const fvec4 gmLo = *(const fvec4*)(gamma + dLo);
    const fvec4 gmHi = *(const fvec4*)(gamma + dHi);
    const fvec4 btLo = *(const fvec4*)(beta + dLo);
    const fvec4 btHi = *(const fvec4*)(beta + dHi);

    fvec4 xLo0, xHi0, xLo1, xHi1, xLo2, xHi2, xLo3, xHi3;

    auto load_tok = [&](int tok, fvec4 pl, fvec4 ph, fvec4& lo, fvec4& hi) {
        const float* tr = token_table + (size_t)tok * Dc;
        lo = *(const fvec4*)(tr + dLo) + pl;
        hi = *(const fvec4*)(tr + dHi) + ph;
    };
    load_tok(tk[0], pLo[0], pHi[0], xLo0, xHi0);
    load_tok(tk[1], pLo[1], pHi[1], xLo1, xHi1);
    load_tok(tk[2], pLo[2], pHi[2], xLo2, xHi2);
    load_tok(tk[3], pLo[3], pHi[3], xLo3, xHi3);

    auto add_spatial = [&](int tok, int pkv, fvec4& lo, fvec4& hi) {
        if (tok <= 9) {                      // wave-uniform branch
            const int rI = pkv >> 5, cI = pkv & 31;
            const float* fr = g_frow + (size_t)rI * Dc;
            const float* fc = g_fcol + (size_t)cI * Dc;
            lo += *(const fvec4*)(fr + dLo) + *(const fvec4*)(fc + dLo);
            hi += *(const fvec4*)(fr + dHi) + *(const fvec4*)(fc + dHi);
        }
    };
    add_spatial(tk[0], pk[0], xLo0, xHi0);
    add_spatial(tk[1], pk[1], xLo1, xHi1);
    add_spatial(tk[2], pk[2], xLo2, xHi2);
    add_spatial(tk[3], pk[3], xLo3, xHi3);

    auto psum = [](fvec4 lo, fvec4 hi, float& s, float& q) {
        s = lo.x + lo.y + lo.z + lo.w + hi.x + hi.y + hi.z + hi.w;
        q = 0.f;
        q = fmaf(lo.x, lo.x, q); q = fmaf(lo.y, lo.y, q);
        q = fmaf(lo.z, lo.z, q); q = fmaf(lo.w, lo.w, q);
        q = fmaf(hi.x, hi.x, q); q = fmaf(hi.y, hi.y, q);
        q = fmaf(hi.z, hi.z, q); q = fmaf(hi.w, hi.w, q);
    };
    float s0, q0, s1, q1, s2, q2, s3, q3;
    psum(xLo0, xHi0, s0, q0);
    psum(xLo1, xHi1, s1, q1);
    psum(xLo2, xHi2, s2, q2);
    psum(xLo3, xHi3, s3, q3);

    // 8 independent butterfly chains interleaved
#pragma unroll
    for (int m = 1; m < 64; m <<= 1) {
        s0 += __shfl_xor(s0, m);
        s1 += __shfl_xor(s1, m);
        s2 += __shfl_xor(s2, m);
        s3 += __shfl_xor(s3, m);
        q0 += __shfl_xor(q0, m);
        q1 += __shfl_xor(q1, m);
        q2 += __shfl_xor(q2, m);
        q3 += __shfl_xor(q3, m);
    }

    const float mu0 = s0 * (1.0f / Dc);
    const float mu1 = s1 * (1.0f / Dc);
    const float mu2 = s2 * (1.0f / Dc);
    const float mu3 = s3 * (1.0f / Dc);
    const float inv0 = rsqrtf(fmaf(-mu0, mu0, q0 * (1.0f / Dc)) + 1e-5f);
    const float inv1 = rsqrtf(fmaf(-mu1, mu1, q1 * (1.0f / Dc)) + 1e-5f);
    const float inv2 = rsqrtf(fmaf(-mu2, mu2, q2 * (1.0f / Dc)) + 1e-5f);
    const float inv3 = rsqrtf(fmaf(-mu3, mu3, q3 * (1.0f / Dc)) + 1e-5f);

    auto store_row = [&](fvec4 lo, fvec4 hi, float mu, float inv, int base) {
        fvec4 yl = (lo - mu) * inv * gmLo + btLo;
        fvec4 yh = (hi - mu) * inv * gmHi + btHi;
        float* op = out + (size_t)base * Dc;
        __builtin_nontemporal_store(yl, (fvec4*)(op + dLo));   // dense 1KB/instr
        __builtin_nontemporal_store(yh, (fvec4*)(op + dHi));   // dense 1KB/instr
    };
    // ONE contiguous 8KB run: rows t, t+1, t+2, t+3 of batch row b
    store_row(xLo0, xHi0, mu0, inv0, idx);
    store_row(xLo1, xHi1, mu1, inv1, idx + 1);
    store_row(xLo2, xHi2, mu2, inv2, idx + 2);
    store_row(xLo3, xHi3, mu3, inv3, idx + 3);
}

extern "C" void kernel_launch(void* const* d_in, const int* in_sizes, int n_in,
                              void* d_out, int out_size, void* d_ws, size_t ws_size,
                              hipStream_t stream) {
    const int*   ids         = (const int*)d_in[0];
    const float* token_table = (const float*)d_in[1];
    const float* pos_table   = (const float*)d_in[2];
    const float* row_table   = (const float*)d_in[3];
    const float* col_table   = (const float*)d_in[4];
    const float* w_spatial   = (const float*)d_in[5];
    const float* ln_gamma    = (const float*)d_in[6];
    const float* ln_beta     = (const float*)d_in[7];
    float* out = (float*)d_out;

    (void)d_ws; (void)ws_size;   // ws poison is unconditional; we don't add to it

    hipLaunchKernelGGL(scan_pre_kernel, dim3(76), dim3(1024), 0, stream,
                       ids, row_table, col_table, w_spatial);
    hipLaunchKernelGGL(fuse_ln_kernel, dim3(Bc * Tc / 16), dim3(256), 0, stream,
                       ids, token_table, pos_table, ln_gamma, ln_beta, out);
}

// Round 12
// 180.760 us; speedup vs baseline: 1.0001x; 1.0001x over previous
//
#include <hip/hip_runtime.h>
#include <hip/hip_bf16.h>

constexpr int PAD_T = 10, BOS_T = 11, EOS_T = 12, ROW_T = 13, SEP_T = 14;
constexpr int Bc = 16, Tc = 4096, Dc = 512;
constexpr int MAXH = 30, MAXW = 30;

typedef float fvec4 __attribute__((ext_vector_type(4)));

// Scratch in module-scope device globals (the d_ws poison is unconditional,
// so d_ws is unused entirely). scan_pre_kernel fully rewrites all three
// every launch before fuse_ln_kernel reads them: no stale-data hazard.
__device__ __align__(16) int   g_packed[Bc * Tc];        // 256 KiB
__device__ __align__(16) float g_frow[MAXH * Dc];        // 60 KiB
__device__ __align__(16) float g_fcol[MAXW * Dc];        // 60 KiB

// Composable transition summary of a token chunk.
struct Summ { int r, c0, c1, g0, g1, rk, ck; };

__device__ inline void tok_update(int tok, Summ& s) {
    if (tok == BOS_T)      { s.g0 = 1; s.g1 = 1; s.r = 0; s.c0 = 0; s.c1 = 0; s.rk = 0; s.ck = 0; }
    else if (tok == SEP_T) { s.r = 0; s.c0 = 0; s.c1 = 0; s.rk = 0; s.ck = 0; }
    else if (tok == ROW_T) { s.r += 1; s.c0 = 0; s.c1 = 0; s.ck = 0; }
    else if (tok == EOS_T || tok == PAD_T) { s.g0 = 0; s.g1 = 0; }
    else { s.c0 += s.g0; s.c1 += s.g1; }   // digit 0..9
}

__device__ inline Summ compose(const Summ& a, const Summ& b) {
    Summ o;
    o.g0 = a.g0 ? b.g1 : b.g0;
    o.g1 = a.g1 ? b.g1 : b.g0;
    o.r  = b.rk ? a.r + b.r : b.r;
    o.rk = a.rk & b.rk;
    int cm0 = a.g0 ? b.c1 : b.c0;
    int cm1 = a.g1 ? b.c1 : b.c0;
    o.c0 = b.ck ? a.c0 + cm0 : cm0;
    o.c1 = b.ck ? a.c1 + cm1 : cm1;
    o.ck = a.ck & b.ck;
    return o;
}

__device__ inline void apply_state(const Summ& s, int& r, int& c, int& g) {
    int cm = g ? s.c1 : s.c0;
    r = s.rk ? r + s.r : s.r;
    c = s.ck ? c + cm : cm;
    g = g ? s.g1 : s.g0;
}

// ---------------------------------------------------------------------------
// Dispatch 1 (merged): blocks 0..15 = parallel automaton scan; blocks 16..75 =
// einsum collapse Frow = row_table @ W[:, :256]^T, Fcol = col_table @ W[:, 256:]^T.
// ---------------------------------------------------------------------------
__global__ __launch_bounds__(1024) void scan_pre_kernel(
        const int* __restrict__ ids,
        const float* __restrict__ row_table, const float* __restrict__ col_table,
        const float* __restrict__ w) {
    if (blockIdx.x < 16) {
        const int b = blockIdx.x;
        const int tid = threadIdx.x;          // 0..1023
        const int lane = tid & 63, wid = tid >> 6;

        const int4 tk4 = *(const int4*)(ids + b * Tc + tid * 4);
        int tks[4] = {tk4.x, tk4.y, tk4.z, tk4.w};

        Summ s{0, 0, 0, 0, 1, 1, 1};
#pragma unroll
        for (int j = 0; j < 4; ++j) tok_update(tks[j], s);

        Summ inc = s;
#pragma unroll
        for (int d = 1; d < 64; d <<= 1) {
            Summ o;
            o.r  = __shfl_up(inc.r, d);
            o.c0 = __shfl_up(inc.c0, d);
            o.c1 = __shfl_up(inc.c1, d);
            o.g0 = __shfl_up(inc.g0, d);
            o.g1 = __shfl_up(inc.g1, d);
            o.rk = __shfl_up(inc.rk, d);
            o.ck = __shfl_up(inc.ck, d);
            if (lane >= d) inc = compose(o, inc);
        }

        __shared__ int lsum[16][7];
        if (lane == 63) {
            lsum[wid][0] = inc.r;  lsum[wid][1] = inc.c0; lsum[wid][2] = inc.c1;
            lsum[wid][3] = inc.g0; lsum[wid][4] = inc.g1;
            lsum[wid][5] = inc.rk; lsum[wid][6] = inc.ck;
        }
        __syncthreads();

        int wr = 0, wc = 0, wg = 0;
        for (int w2 = 0; w2 < wid; ++w2) {
            Summ t;
            t.r  = lsum[w2][0]; t.c0 = lsum[w2][1]; t.c1 = lsum[w2][2];
            t.g0 = lsum[w2][3]; t.g1 = lsum[w2][4];
            t.rk = lsum[w2][5]; t.ck = lsum[w2][6];
            apply_state(t, wr, wc, wg);
        }

        Summ ex;
        ex.r  = __shfl_up(inc.r, 1);  ex.c0 = __shfl_up(inc.c0, 1);
        ex.c1 = __shfl_up(inc.c1, 1); ex.g0 = __shfl_up(inc.g0, 1);
        ex.g1 = __shfl_up(inc.g1, 1); ex.rk = __shfl_up(inc.rk, 1);
        ex.ck = __shfl_up(inc.ck, 1);
        if (lane == 0) { ex = Summ{0, 0, 0, 0, 1, 1, 1}; }
        int row = wr, col = wc, grid = wg;
        apply_state(ex, row, col, grid);

        int o4[4];
#pragma unroll
        for (int j = 0; j < 4; ++j) {
            int tok = tks[j];
            int gc = grid & (tok <= 9);
            int er = gc ? min(row, MAXH - 1) : 0;
            int ec = gc ? min(col, MAXW - 1) : 0;
            o4[j] = (er << 5) | ec;
            if (tok == BOS_T)      { grid = 1; row = 0; col = 0; }
            else if (tok == SEP_T) { row = 0; col = 0; }
            else if (tok == ROW_T) { row += 1; col = 0; }
            else if (tok == EOS_T || tok == PAD_T) { grid = 0; }
            else { col += gc; }
        }
        *(int4*)(g_packed + b * Tc + tid * 4) = make_int4(o4[0], o4[1], o4[2], o4[3]);
    } else {
        const int blk = blockIdx.x - 16;
        const int which = blk / 30;            // 0 -> Frow, 1 -> Fcol
        const int rr = blk % 30;
        const float* src = which ? (col_table + rr * 256) : (row_table + rr * 256);
        float* dst = which ? (g_fcol + rr * Dc) : (g_frow + rr * Dc);
        const int doff = which ? 256 : 0;

        __shared__ __align__(16) float sv[256];
        __shared__ float part[512];
        if (threadIdx.x < 256) sv[threadIdx.x] = src[threadIdx.x];
        __syncthreads();

        const int e    = threadIdx.x & 511;
        const int half = threadIdx.x >> 9;     // split-k: 2 threads per output
        const float4* a4 = (const float4*)sv + half * 32;
        const float4* w4 = (const float4*)(w + (size_t)e * Dc + doff) + half * 32;
        float acc = 0.f;
#pragma unroll 8
        for (int k = 0; k < 32; ++k) {
            float4 a = a4[k];
            float4 wb = w4[k];
            acc += a.x * wb.x + a.y * wb.y + a.z * wb.z + a.w * wb.w;
        }
        if (half) part[e] = acc;
        __syncthreads();
        if (!half) dst[e] = acc + part[e];
    }
}

// ---------------------------------------------------------------------------
// Dispatch 2: fused embed-add + LayerNorm. PERSISTENT LINEAR SWEEP: 1024
// blocks x 4 waves; wave w owns rows (b = w>>8, t = (w&255)*16 .. +16) and
// processes them in 4 iterations of the proven round-10 body (4 rows/iter,
// dense dLo/dHi lanes, cached stores -- NT lost 3x). Each wave now emits ONE
// contiguous ascending 32KB store stream (block: 128KB) instead of an
// isolated one-shot 8KB granule -- the last structural difference vs the
// 6.4TB/s fill, whose threads sweep long sequential ranges. Unlike round 6's
// failed persistent kernel this keeps 4-row MLP per iteration and sequential
// (not 1024-row-strided) iteration advance. ids/packed prefetched one
// iteration ahead; gamma/beta hoisted out of the loop.
// ---------------------------------------------------------------------------
__global__ __launch_bounds__(256) void fuse_ln_kernel(
        const int* __restrict__ ids,
        const float* __restrict__ token_table, const float* __restrict__ pos_table,
        const float* __restrict__ gamma, const float* __restrict__ beta,
        float* __restrict__ out) {
    const int wave = threadIdx.x >> 6;
    const int lane = threadIdx.x & 63;
    const int w  = blockIdx.x * 4 + wave;    // wave id in [0, 4096)
    const int b  = w >> 8;                   // batch row (0..15), slowest
    const int tb = (w & 255) << 4;           // 16-row window start
    const int dLo = lane * 4;                // dense low half  [0,256)
    const int dHi = 256 + lane * 4;          // dense high half [256,512)

    const fvec4 gmLo = *(const fvec4*)(gamma + dLo);
    const fvec4 gmHi = *(const fvec4*)(gamma + dHi);
    const fvec4 btLo = *(const fvec4*)(beta + dLo);
    const fvec4 btHi = *(const fvec4*)(beta + dHi);

    // iteration-0 ids/packed
    int4 tk4 = *(const int4*)(ids + b * Tc + tb);
    int4 pk4 = *(const int4*)(g_packed + b * Tc + tb);

#pragma unroll 1
    for (int it = 0; it < 4; ++it) {
        const int idx = b * Tc + tb + it * 4;    // 4 consecutive rows

        // prefetch next iteration's ids/packed (clamped at the tail)
        const int pidx = (it < 3) ? (idx + 4) : idx;
        const int4 ntk = *(const int4*)(ids + pidx);
        const int4 npk = *(const int4*)(g_packed + pidx);

        const int tk[4] = {tk4.x, tk4.y, tk4.z, tk4.w};
        const int pk[4] = {pk4.x, pk4.y, pk4.z, pk4.w};

        // pos rows for the 4 current timesteps
        const float* pt = pos_table + (size_t)(tb + it * 4) * Dc;
        fvec4 pLo[4], pHi[4];
#pragma unroll
        for (int k = 0; k < 4; ++k) {
            pLo[k] = *(const fvec4*)(pt + k * Dc + dLo);
            pHi[k] = *(const fvec4*)(pt + k * Dc + dHi);
        }

        fvec4 xLo0, xHi0, xLo1, xHi1, xLo2, xHi2, xLo3, xHi3;

        auto load_tok = [&](int tok, fvec4 pl, fvec4 ph, fvec4& lo, fvec4& hi) {
            const float* tr = token_table + (size_t)tok * Dc;
            lo = *(const fvec4*)(tr + dLo) + pl;
            hi = *(const fvec4*)(tr + dHi) + ph;
        };
        load_tok(tk[0], pLo[0], pHi[0], xLo0, xHi0);
        load_tok(tk[1], pLo[1], pHi[1], xLo1, xHi1);
        load_tok(tk[2], pLo[2], pHi[2], xLo2, xHi2);
        load_tok(tk[3], pLo[3], pHi[3], xLo3, xHi3);

        auto add_spatial = [&](int tok, int pkv, fvec4& lo, fvec4& hi) {
            if (tok <= 9) {                  // wave-uniform branch
                const int rI = pkv >> 5, cI = pkv & 31;
                const float* fr = g_frow + (size_t)rI * Dc;
                const float* fc = g_fcol + (size_t)cI * Dc;
                lo += *(const fvec4*)(fr + dLo) + *(const fvec4*)(fc + dLo);
                hi += *(const fvec4*)(fr + dHi) + *(const fvec4*)(fc + dHi);
            }
        };
        add_spatial(tk[0], pk[0], xLo0, xHi0);
        add_spatial(tk[1], pk[1], xLo1, xHi1);
        add_spatial(tk[2], pk[2], xLo2, xHi2);
        add_spatial(tk[3], pk[3], xLo3, xHi3);

        auto psum = [](fvec4 lo, fvec4 hi, float& s, float& q) {
            s = lo.x + lo.y + lo.z + lo.w + hi.x + hi.y + hi.z + hi.w;
            q = 0.f;
            q = fmaf(lo.x, lo.x, q); q = fmaf(lo.y, lo.y, q);
            q = fmaf(lo.z, lo.z, q); q = fmaf(lo.w, lo.w, q);
            q = fmaf(hi.x, hi.x, q); q = fmaf(hi.y, hi.y, q);
            q = fmaf(hi.z, hi.z, q); q = fmaf(hi.w, hi.w, q);
        };
        float s0, q0, s1, q1, s2, q2, s3, q3;
        psum(xLo0, xHi0, s0, q0);
        psum(xLo1, xHi1, s1, q1);
        psum(xLo2, xHi2, s2, q2);
        psum(xLo3, xHi3, s3, q3);

        // 8 independent butterfly chains interleaved
#pragma unroll
        for (int m = 1; m < 64; m <<= 1) {
            s0 += __shfl_xor(s0, m);
            s1 += __shfl_xor(s1, m);
            s2 += __shfl_xor(s2, m);
            s3 += __shfl_xor(s3, m);
            q0 += __shfl_xor(q0, m);
            q1 += __shfl_xor(q1, m);
            q2 += __shfl_xor(q2, m);
            q3 += __shfl_xor(q3, m);
        }

        const float mu0 = s0 * (1.0f / Dc);
        const float mu1 = s1 * (1.0f / Dc);
        const float mu2 = s2 * (1.0f / Dc);
        const float mu3 = s3 * (1.0f / Dc);
        const float inv0 = rsqrtf(fmaf(-mu0, mu0, q0 * (1.0f / Dc)) + 1e-5f);
        const float inv1 = rsqrtf(fmaf(-mu1, mu1, q1 * (1.0f / Dc)) + 1e-5f);
        const float inv2 = rsqrtf(fmaf(-mu2, mu2, q2 * (1.0f / Dc)) + 1e-5f);
        const float inv3 = rsqrtf(fmaf(-mu3, mu3, q3 * (1.0f / Dc)) + 1e-5f);

        auto store_row = [&](fvec4 lo, fvec4 hi, float mu, float inv, int base) {
            fvec4 yl = (lo - mu) * inv * gmLo + btLo;
            fvec4 yh = (hi - mu) * inv * gmHi + btHi;
            float* op = out + (size_t)base * Dc;
            *(fvec4*)(op + dLo) = yl;        // dense 1KB across the wave
            *(fvec4*)(op + dHi) = yh;        // dense 1KB across the wave
        };
        store_row(xLo0, xHi0, mu0, inv0, idx);
        store_row(xLo1, xHi1, mu1, inv1, idx + 1);
        store_row(xLo2, xHi2, mu2, inv2, idx + 2);
        store_row(xLo3, xHi3, mu3, inv3, idx + 3);

        tk4 = ntk; pk4 = npk;
    }
}

extern "C" void kernel_launch(void* const* d_in, const int* in_sizes, int n_in,
                              void* d_out, int out_size, void* d_ws, size_t ws_size,
                              hipStream_t stream) {
    const int*   ids         = (const int*)d_in[0];
    const float* token_table = (const float*)d_in[1];
    const float* pos_table   = (const float*)d_in[2];
    const float* row_table   = (const float*)d_in[3];
    const float* col_table   = (const float*)d_in[4];
    const float* w_spatial   = (const float*)d_in[5];
    const float* ln_gamma    = (const float*)d_in[6];
    const float* ln_beta     = (const float*)d_in[7];
    float* out = (float*)d_out;

    (void)d_ws; (void)ws_size;   // ws poison is unconditional; we don't add to it

    hipLaunchKernelGGL(scan_pre_kernel, dim3(76), dim3(1024), 0, stream,
                       ids, row_table, col_table, w_spatial);
    hipLaunchKernelGGL(fuse_ln_kernel, dim3(1024), dim3(256), 0, stream,
                       ids, token_table, pos_table, ln_gamma, ln_beta, out);
}

// Round 13
// 175.670 us; speedup vs baseline: 1.0290x; 1.0290x over previous
//
#include <hip/hip_runtime.h>
#include <hip/hip_bf16.h>

constexpr int PAD_T = 10, BOS_T = 11, EOS_T = 12, ROW_T = 13, SEP_T = 14;
constexpr int Bc = 16, Tc = 4096, Dc = 512;
constexpr int MAXH = 30, MAXW = 30;

typedef float fvec4 __attribute__((ext_vector_type(4)));

// Scratch in module-scope device globals (the d_ws poison is unconditional,
// so d_ws is unused entirely). scan_pre_kernel fully rewrites all three
// every launch before fuse_ln_kernel reads them: no stale-data hazard.
__device__ __align__(16) int   g_packed[Bc * Tc];        // 256 KiB
__device__ __align__(16) float g_frow[MAXH * Dc];        // 60 KiB
__device__ __align__(16) float g_fcol[MAXW * Dc];        // 60 KiB

// Composable transition summary of a token chunk.
struct Summ { int r, c0, c1, g0, g1, rk, ck; };

__device__ inline void tok_update(int tok, Summ& s) {
    if (tok == BOS_T)      { s.g0 = 1; s.g1 = 1; s.r = 0; s.c0 = 0; s.c1 = 0; s.rk = 0; s.ck = 0; }
    else if (tok == SEP_T) { s.r = 0; s.c0 = 0; s.c1 = 0; s.rk = 0; s.ck = 0; }
    else if (tok == ROW_T) { s.r += 1; s.c0 = 0; s.c1 = 0; s.ck = 0; }
    else if (tok == EOS_T || tok == PAD_T) { s.g0 = 0; s.g1 = 0; }
    else { s.c0 += s.g0; s.c1 += s.g1; }   // digit 0..9
}

__device__ inline Summ compose(const Summ& a, const Summ& b) {
    Summ o;
    o.g0 = a.g0 ? b.g1 : b.g0;
    o.g1 = a.g1 ? b.g1 : b.g0;
    o.r  = b.rk ? a.r + b.r : b.r;
    o.rk = a.rk & b.rk;
    int cm0 = a.g0 ? b.c1 : b.c0;
    int cm1 = a.g1 ? b.c1 : b.c0;
    o.c0 = b.ck ? a.c0 + cm0 : cm0;
    o.c1 = b.ck ? a.c1 + cm1 : cm1;
    o.ck = a.ck & b.ck;
    return o;
}

__device__ inline void apply_state(const Summ& s, int& r, int& c, int& g) {
    int cm = g ? s.c1 : s.c0;
    r = s.rk ? r + s.r : s.r;
    c = s.ck ? c + cm : cm;
    g = g ? s.g1 : s.g0;
}

// ---------------------------------------------------------------------------
// Dispatch 1 (merged): blocks 0..15 = parallel automaton scan; blocks 16..75 =
// einsum collapse Frow = row_table @ W[:, :256]^T, Fcol = col_table @ W[:, 256:]^T.
// ---------------------------------------------------------------------------
__global__ __launch_bounds__(1024) void scan_pre_kernel(
        const int* __restrict__ ids,
        const float* __restrict__ row_table, const float* __restrict__ col_table,
        const float* __restrict__ w) {
    if (blockIdx.x < 16) {
        const int b = blockIdx.x;
        const int tid = threadIdx.x;          // 0..1023
        const int lane = tid & 63, wid = tid >> 6;

        const int4 tk4 = *(const int4*)(ids + b * Tc + tid * 4);
        int tks[4] = {tk4.x, tk4.y, tk4.z, tk4.w};

        Summ s{0, 0, 0, 0, 1, 1, 1};
#pragma unroll
        for (int j = 0; j < 4; ++j) tok_update(tks[j], s);

        Summ inc = s;
#pragma unroll
        for (int d = 1; d < 64; d <<= 1) {
            Summ o;
            o.r  = __shfl_up(inc.r, d);
            o.c0 = __shfl_up(inc.c0, d);
            o.c1 = __shfl_up(inc.c1, d);
            o.g0 = __shfl_up(inc.g0, d);
            o.g1 = __shfl_up(inc.g1, d);
            o.rk = __shfl_up(inc.rk, d);
            o.ck = __shfl_up(inc.ck, d);
            if (lane >= d) inc = compose(o, inc);
        }

        __shared__ int lsum[16][7];
        if (lane == 63) {
            lsum[wid][0] = inc.r;  lsum[wid][1] = inc.c0; lsum[wid][2] = inc.c1;
            lsum[wid][3] = inc.g0; lsum[wid][4] = inc.g1;
            lsum[wid][5] = inc.rk; lsum[wid][6] = inc.ck;
        }
        __syncthreads();

        int wr = 0, wc = 0, wg = 0;
        for (int w2 = 0; w2 < wid; ++w2) {
            Summ t;
            t.r  = lsum[w2][0]; t.c0 = lsum[w2][1]; t.c1 = lsum[w2][2];
            t.g0 = lsum[w2][3]; t.g1 = lsum[w2][4];
            t.rk = lsum[w2][5]; t.ck = lsum[w2][6];
            apply_state(t, wr, wc, wg);
        }

        Summ ex;
        ex.r  = __shfl_up(inc.r, 1);  ex.c0 = __shfl_up(inc.c0, 1);
        ex.c1 = __shfl_up(inc.c1, 1); ex.g0 = __shfl_up(inc.g0, 1);
        ex.g1 = __shfl_up(inc.g1, 1); ex.rk = __shfl_up(inc.rk, 1);
        ex.ck = __shfl_up(inc.ck, 1);
        if (lane == 0) { ex = Summ{0, 0, 0, 0, 1, 1, 1}; }
        int row = wr, col = wc, grid = wg;
        apply_state(ex, row, col, grid);

        int o4[4];
#pragma unroll
        for (int j = 0; j < 4; ++j) {
            int tok = tks[j];
            int gc = grid & (tok <= 9);
            int er = gc ? min(row, MAXH - 1) : 0;
            int ec = gc ? min(col, MAXW - 1) : 0;
            o4[j] = (er << 5) | ec;
            if (tok == BOS_T)      { grid = 1; row = 0; col = 0; }
            else if (tok == SEP_T) { row = 0; col = 0; }
            else if (tok == ROW_T) { row += 1; col = 0; }
            else if (tok == EOS_T || tok == PAD_T) { grid = 0; }
            else { col += gc; }
        }
        *(int4*)(g_packed + b * Tc + tid * 4) = make_int4(o4[0], o4[1], o4[2], o4[3]);
    } else {
        const int blk = blockIdx.x - 16;
        const int which = blk / 30;            // 0 -> Frow, 1 -> Fcol
        const int rr = blk % 30;
        const float* src = which ? (col_table + rr * 256) : (row_table + rr * 256);
        float* dst = which ? (g_fcol + rr * Dc) : (g_frow + rr * Dc);
        const int doff = which ? 256 : 0;

        __shared__ __align__(16) float sv[256];
        __shared__ float part[512];
        if (threadIdx.x < 256) sv[threadIdx.x] = src[threadIdx.x];
        __syncthreads();

        const int e    = threadIdx.x & 511;
        const int half = threadIdx.x >> 9;     // split-k: 2 threads per output
        const float4* a4 = (const float4*)sv + half * 32;
        const float4* w4 = (const float4*)(w + (size_t)e * Dc + doff) + half * 32;
        float acc = 0.f;
#pragma unroll 8
        for (int k = 0; k < 32; ++k) {
            float4 a = a4[k];
            float4 wb = w4[k];
            acc += a.x * wb.x + a.y * wb.y + a.z * wb.z + a.w * wb.w;
        }
        if (half) part[e] = acc;
        __syncthreads();
        if (!half) dst[e] = acc + part[e];
    }
}

// ---------------------------------------------------------------------------
// Dispatch 2: fused embed-add + LayerNorm. BEST-MEASURED CONFIG (175.4us,
// round 9 of this session): 4 tokens/wave ((b0,b0+8) x (t,t+1)), dense
// dLo/dHi lane mapping (every 16B vector op = 64x16B contiguous 1KB), and
// STORE-LOCALITY wave mapping: b0 = g>>11 slowest, t-pair fastest, so
// concurrently-resident waves write adjacent addresses (DRAM row-buffer
// locality; -11us vs b-fastest). Cached stores: NT measured slower in all
// three layouts tried (r0/r3 null, r2 2.3x amplification, r11 +5us).
// Session ledger: single-stream r10 +2, NT r11 +5, persistent sweep r12 +5,
// persistent depth-1 prefetch r6 +23 -- this config is the floor of the
// explored space; residual vs pure-write roofline ~24us = mixed read+write
// stream at ~3.2TB/s combined vs 6.3TB/s write-only fill.
// ---------------------------------------------------------------------------
__global__ __launch_bounds__(256) void fuse_ln_kernel(
        const int* __restrict__ ids,
        const float* __restrict__ token_table, const float* __restrict__ pos_table,
        const float* __restrict__ gamma, const float* __restrict__ beta,
        float* __restrict__ out) {
    const int wave = threadIdx.x >> 6;
    const int lane = threadIdx.x & 63;
    const int g2 = blockIdx.x * 4 + wave;    // wave id in [0, 16384)
    const int b0 = g2 >> 11;                 // batch pair, SLOWEST (store locality)
    const int t  = (g2 & 2047) << 1;         // even t, FASTEST across waves
    const int idx00 = b0 * Tc + t;           // (b0,   t)
    const int idx10 = idx00 + 8 * Tc;        // (b0+8, t)
    const int dLo = lane * 4;                // dense low half  [0,256)
    const int dHi = 256 + lane * 4;          // dense high half [256,512)

    // token ids + packed coords: 8B vector loads, 2 tokens each
    const int2 tkA = *(const int2*)(ids + idx00);       // (b0,t), (b0,t+1)
    const int2 tkB = *(const int2*)(ids + idx10);       // (b0+8,t), (b0+8,t+1)
    const int2 pkA = *(const int2*)(g_packed + idx00);
    const int2 pkB = *(const int2*)(g_packed + idx10);

    // pos rows for t and t+1 (dense 1KB per instruction)
    const float* pt = pos_table + (size_t)t * Dc;
    const fvec4 pLo0 = *(const fvec4*)(pt + dLo);
    const fvec4 pHi0 = *(const fvec4*)(pt + dHi);
    const fvec4 pLo1 = *(const fvec4*)(pt + Dc + dLo);
    const fvec4 pHi1 = *(const fvec4*)(pt + Dc + dHi);

    const fvec4 gmLo = *(const fvec4*)(gamma + dLo);
    const fvec4 gmHi = *(const fvec4*)(gamma + dHi);
    const fvec4 btLo = *(const fvec4*)(beta + dLo);
    const fvec4 btHi = *(const fvec4*)(beta + dHi);

    fvec4 xLo00, xHi00, xLo01, xHi01, xLo10, xHi10, xLo11, xHi11;

    auto load_tok = [&](int tok, fvec4 pl, fvec4 ph, fvec4& lo, fvec4& hi) {
        const float* tr = token_table + (size_t)tok * Dc;
        lo = *(const fvec4*)(tr + dLo) + pl;
        hi = *(const fvec4*)(tr + dHi) + ph;
    };
    load_tok(tkA.x, pLo0, pHi0, xLo00, xHi00);
    load_tok(tkA.y, pLo1, pHi1, xLo01, xHi01);
    load_tok(tkB.x, pLo0, pHi0, xLo10, xHi10);
    load_tok(tkB.y, pLo1, pHi1, xLo11, xHi11);

    auto add_spatial = [&](int tok, int pk, fvec4& lo, fvec4& hi) {
        if (tok <= 9) {                      // wave-uniform branch
            const int rI = pk >> 5, cI = pk & 31;
            const float* fr = g_frow + (size_t)rI * Dc;
            const float* fc = g_fcol + (size_t)cI * Dc;
            lo += *(const fvec4*)(fr + dLo) + *(const fvec4*)(fc + dLo);
            hi += *(const fvec4*)(fr + dHi) + *(const fvec4*)(fc + dHi);
        }
    };
    add_spatial(tkA.x, pkA.x, xLo00, xHi00);
    add_spatial(tkA.y, pkA.y, xLo01, xHi01);
    add_spatial(tkB.x, pkB.x, xLo10, xHi10);
    add_spatial(tkB.y, pkB.y, xLo11, xHi11);

    auto psum = [](fvec4 lo, fvec4 hi, float& s, float& q) {
        s = lo.x + lo.y + lo.z + lo.w + hi.x + hi.y + hi.z + hi.w;
        q = 0.f;
        q = fmaf(lo.x, lo.x, q); q = fmaf(lo.y, lo.y, q);
        q = fmaf(lo.z, lo.z, q); q = fmaf(lo.w, lo.w, q);
        q = fmaf(hi.x, hi.x, q); q = fmaf(hi.y, hi.y, q);
        q = fmaf(hi.z, hi.z, q); q = fmaf(hi.w, hi.w, q);
    };
    float s00, q00, s01, q01, s10, q10, s11, q11;
    psum(xLo00, xHi00, s00, q00);
    psum(xLo01, xHi01, s01, q01);
    psum(xLo10, xHi10, s10, q10);
    psum(xLo11, xHi11, s11, q11);

    // 8 independent butterfly chains interleaved
#pragma unroll
    for (int m = 1; m < 64; m <<= 1) {
        s00 += __shfl_xor(s00, m);
        s01 += __shfl_xor(s01, m);
        s10 += __shfl_xor(s10, m);
        s11 += __shfl_xor(s11, m);
        q00 += __shfl_xor(q00, m);
        q01 += __shfl_xor(q01, m);
        q10 += __shfl_xor(q10, m);
        q11 += __shfl_xor(q11, m);
    }

    const float mu00 = s00 * (1.0f / Dc);
    const float mu01 = s01 * (1.0f / Dc);
    const float mu10 = s10 * (1.0f / Dc);
    const float mu11 = s11 * (1.0f / Dc);
    const float inv00 = rsqrtf(fmaf(-mu00, mu00, q00 * (1.0f / Dc)) + 1e-5f);
    const float inv01 = rsqrtf(fmaf(-mu01, mu01, q01 * (1.0f / Dc)) + 1e-5f);
    const float inv10 = rsqrtf(fmaf(-mu10, mu10, q10 * (1.0f / Dc)) + 1e-5f);
    const float inv11 = rsqrtf(fmaf(-mu11, mu11, q11 * (1.0f / Dc)) + 1e-5f);

    auto store_row = [&](fvec4 lo, fvec4 hi, float mu, float inv, int base) {
        fvec4 yl = (lo - mu) * inv * gmLo + btLo;
        fvec4 yh = (hi - mu) * inv * gmHi + btHi;
        float* op = out + (size_t)base * Dc;
        *(fvec4*)(op + dLo) = yl;            // dense 1KB across the wave
        *(fvec4*)(op + dHi) = yh;            // dense 1KB across the wave
    };
    store_row(xLo00, xHi00, mu00, inv00, idx00);
    store_row(xLo01, xHi01, mu01, inv01, idx00 + 1);
    store_row(xLo10, xHi10, mu10, inv10, idx10);
    store_row(xLo11, xHi11, mu11, inv11, idx10 + 1);
}

extern "C" void kernel_launch(void* const* d_in, const int* in_sizes, int n_in,
                              void* d_out, int out_size, void* d_ws, size_t ws_size,
                              hipStream_t stream) {
    const int*   ids         = (const int*)d_in[0];
    const float* token_table = (const float*)d_in[1];
    const float* pos_table   = (const float*)d_in[2];
    const float* row_table   = (const float*)d_in[3];
    const float* col_table   = (const float*)d_in[4];
    const float* w_spatial   = (const float*)d_in[5];
    const float* ln_gamma    = (const float*)d_in[6];
    const float* ln_beta     = (const float*)d_in[7];
    float* out = (float*)d_out;

    (void)d_ws; (void)ws_size;   // ws poison is unconditional; we don't add to it

    hipLaunchKernelGGL(scan_pre_kernel, dim3(76), dim3(1024), 0, stream,
                       ids, row_table, col_table, w_spatial);
    hipLaunchKernelGGL(fuse_ln_kernel, dim3(Bc * Tc / 16), dim3(256), 0, stream,
                       ids, token_table, pos_table, ln_gamma, ln_beta, out);
}